// Round 7
// baseline (177.532 us; speedup 1.0000x reference)
//
#include <hip/hip_runtime.h>
#include <math.h>

#define NBINS 15
#define NCLS  100
#define NHALF 50               // float2 slots per row (2 classes per lane)
#define NSEG  (NBINS * NCLS)   // 1500
#define R     4                // rows per wave per iteration
#define NBLK  512
#define NTHR  1024

// DPP-based wave64 sum on the VALU pipe (no DS ops). ctrl must be literal.
template <int CTRL>
__device__ __forceinline__ float dpp_add_f32(float x) {
    int y = __builtin_amdgcn_update_dpp(0, __float_as_int(x), CTRL, 0xf, 0xf, true);
    return x + __int_as_float(y);
}
__device__ __forceinline__ float wave_sum64(float x) {
    x = dpp_add_f32<0x111>(x);   // row_shr:1
    x = dpp_add_f32<0x112>(x);   // row_shr:2
    x = dpp_add_f32<0x114>(x);   // row_shr:4
    x = dpp_add_f32<0x118>(x);   // row_shr:8
    x = dpp_add_f32<0x142>(x);   // row_bcast:15
    x = dpp_add_f32<0x143>(x);   // row_bcast:31 -> lane 63 = total
    return __int_as_float(__builtin_amdgcn_readlane(__float_as_int(x), 63));
}

__device__ __forceinline__ void load_tile(const float2* __restrict__ base2,
                                          const int* __restrict__ labels,
                                          int r0, int N, bool act, int lane,
                                          float2 (&b)[R], int (&lb)[R])
{
    if (r0 + R <= N) {
        const float2* rp = base2 + (size_t)r0 * NHALF + lane;
        #pragma unroll
        for (int r = 0; r < R; ++r)
            b[r] = act ? rp[r * NHALF] : make_float2(0.0f, 0.0f);
        const int4 l4 = *reinterpret_cast<const int4*>(labels + r0);
        lb[0] = l4.x; lb[1] = l4.y; lb[2] = l4.z; lb[3] = l4.w;
    } else {
        #pragma unroll
        for (int r = 0; r < R; ++r) {
            int row = min(r0 + r, N - 1);
            b[r] = act ? base2[(size_t)row * NHALF + lane] : make_float2(0.0f, 0.0f);
            lb[r] = labels[row];
        }
    }
}

// Fused: per-row softmax + segmented accumulation + last-block final reduce.
// Lane l owns classes 2l, 2l+1 (l<50). Bin-0 hits (~99%) accumulate in
// registers. Double-buffered register prefetch keeps the next tile's loads
// in flight under the current tile's compute (counted vmcnt, not drain-0).
__global__ __launch_bounds__(NTHR, 8)
void ece_fused(const float* __restrict__ logits,
               const int* __restrict__ labels,
               int N,
               double* __restrict__ g_conf,
               unsigned int* __restrict__ g_acc,
               unsigned int* __restrict__ g_done,
               float* __restrict__ out, double inv_nc)
{
    __shared__ float        s_conf[NSEG];
    __shared__ unsigned int s_acc[NSEG];

    const int tid = threadIdx.x;
    for (int i = tid; i < NSEG; i += NTHR) { s_conf[i] = 0.0f; s_acc[i] = 0u; }
    __syncthreads();

    const int  lane = tid & 63;
    const int  wv   = (blockIdx.x << 4) + (tid >> 6);   // 16 waves/block
    const int  nwv  = gridDim.x << 4;
    const bool act  = lane < NHALF;

    float        conf0_a = 0.0f, conf0_b = 0.0f;
    unsigned int acc0_a  = 0u,   acc0_b  = 0u;

    const float2* base2  = reinterpret_cast<const float2*>(logits);
    const int     stride = nwv * R;

    int row0 = wv * R;
    float2 cbuf[R]; int clbl[R];
    if (row0 < N) load_tile(base2, labels, row0, N, act, lane, cbuf, clbl);

    while (row0 < N) {
        const int nrow0 = row0 + stride;
        float2 nbuf[R]; int nlbl[R];
        if (nrow0 < N)                       // prefetch next tile (stays in flight)
            load_tile(base2, labels, nrow0, N, act, lane, nbuf, nlbl);

        // ---- process current tile ----
        float e0[R], e1[R], s[R], invv[R], th[R];
        #pragma unroll
        for (int r = 0; r < R; ++r) {
            e0[r] = act ? __expf(cbuf[r].x) : 0.0f;
            e1[r] = act ? __expf(cbuf[r].y) : 0.0f;
        }
        #pragma unroll
        for (int r = 0; r < R; ++r) s[r] = wave_sum64(e0[r] + e1[r]);
        #pragma unroll
        for (int r = 0; r < R; ++r) {
            invv[r] = __builtin_amdgcn_rcpf(s[r]);       // ~1 ulp
            th[r]   = s[r] * (1.0f / (float)NBINS);      // e > th <=> bin >= 1
        }

        #pragma unroll
        for (int r = 0; r < R; ++r) {
            if (row0 + r >= N) break;
            const float p0 = e0[r] * invv[r];
            const float p1 = e1[r] * invv[r];
            const bool  rare0 = e0[r] > th[r];
            const bool  rare1 = e1[r] > th[r];
            conf0_a += rare0 ? 0.0f : p0;                // branchless hot path
            conf0_b += rare1 ? 0.0f : p1;
            const int  lb   = clbl[r];
            const bool mine = (lane == (lb >> 1));
            if (mine) {
                if (lb & 1) { if (!rare1) ++acc0_b; }
                else        { if (!rare0) ++acc0_a; }
            }
            if (rare0 | rare1) {                         // rare, exec-masked
                if (rare0) {
                    const int b0 = min((int)ceilf(p0 * (float)NBINS) - 1, NBINS - 1);
                    atomicAdd(&s_conf[(2 * lane) * NBINS + b0], p0);
                    if (mine && !(lb & 1)) atomicAdd(&s_acc[(2 * lane) * NBINS + b0], 1u);
                }
                if (rare1) {
                    const int b1 = min((int)ceilf(p1 * (float)NBINS) - 1, NBINS - 1);
                    atomicAdd(&s_conf[(2 * lane + 1) * NBINS + b1], p1);
                    if (mine && (lb & 1)) atomicAdd(&s_acc[(2 * lane + 1) * NBINS + b1], 1u);
                }
            }
        }

        if (nrow0 < N) {
            #pragma unroll
            for (int r = 0; r < R; ++r) { cbuf[r] = nbuf[r]; clbl[r] = nlbl[r]; }
        }
        row0 = nrow0;
    }

    // Flush per-lane register accumulators into the LDS histogram.
    if (act) {
        atomicAdd(&s_conf[(2 * lane) * NBINS], conf0_a);
        if (acc0_a) atomicAdd(&s_acc[(2 * lane) * NBINS], acc0_a);
        atomicAdd(&s_conf[(2 * lane + 1) * NBINS], conf0_b);
        if (acc0_b) atomicAdd(&s_acc[(2 * lane + 1) * NBINS], acc0_b);
    }

    __syncthreads();
    // Flush block partials to global (rotated start to stagger addresses).
    const int rot = (blockIdx.x * 61) % NSEG;
    for (int i = tid; i < NSEG; i += NTHR) {
        int j = i + rot; if (j >= NSEG) j -= NSEG;
        float        c = s_conf[j];
        unsigned int a = s_acc[j];
        if (c != 0.0f) atomicAdd(&g_conf[j], (double)c);
        if (a)         atomicAdd(&g_acc[j], a);
    }

    // Last block performs the final reduction.
    __threadfence();
    __shared__ unsigned int s_last;
    if (tid == 0) s_last = (atomicAdd(g_done, 1u) == gridDim.x - 1) ? 1u : 0u;
    __syncthreads();
    if (s_last) {
        double t = 0.0;
        for (int i = tid; i < NSEG; i += NTHR) {
            double       c = atomicAdd(&g_conf[i], 0.0);   // coherent read
            unsigned int a = atomicAdd(&g_acc[i], 0u);
            t += fabs(c - (double)a);
        }
        #pragma unroll
        for (int off = 32; off; off >>= 1) t += __shfl_xor(t, off);
        __shared__ double sh[16];
        if ((tid & 63) == 0) sh[tid >> 6] = t;
        __syncthreads();
        if (tid == 0) {
            double tot = 0.0;
            #pragma unroll
            for (int i = 0; i < 16; ++i) tot += sh[i];
            out[0] = (float)(tot * inv_nc);
        }
    }
}

extern "C" void kernel_launch(void* const* d_in, const int* in_sizes, int n_in,
                              void* d_out, int out_size, void* d_ws, size_t ws_size,
                              hipStream_t stream)
{
    const float* logits = (const float*)d_in[0];
    const int*   labels = (const int*)d_in[1];
    const int N = in_sizes[1];   // labels count = row count

    double*       g_conf = (double*)d_ws;
    unsigned int* g_acc  = (unsigned int*)(g_conf + NSEG);
    unsigned int* g_done = g_acc + NSEG;

    (void)hipMemsetAsync(d_ws, 0,
                         NSEG * sizeof(double) + (NSEG + 1) * sizeof(unsigned int),
                         stream);

    const double inv_nc = 1.0 / ((double)N * (double)NCLS);
    ece_fused<<<NBLK, NTHR, 0, stream>>>(logits, labels, N,
                                         g_conf, g_acc, g_done,
                                         (float*)d_out, inv_nc);
}